// Round 5
// baseline (205.912 us; speedup 1.0000x reference)
//
#include <hip/hip_runtime.h>
#include <math.h>

#define NWAY 5
#define KSHOT 5
#define PRJ 14
#define DD 64
#define PP 100
#define NQ 1024
#define NS 350
#define NPAIR 70
#define LAMDA 32.0f
#define MARGIN 0.3f
#define PSPLIT 4
#define PCHUNK 25
#define KSPLIT 5

// ---- workspace layout (floats), ~12.6 MB ----
#define VPT_OFF   0          // [70][100][64]  = 448000
#define VPTT_OFF  448000     // [70][6400]     = 448000
#define MM_OFF    896000     // [70][100]      = 7000
#define VNINV_OFF 903000     // [70] pad 128
#define PSUM_OFF  903128     // [70][64] = 4480
#define BASE_OFF  907608     // [5][64]
#define QV_OFF    907928     // [1024][64] = 65536
#define INVQ_OFF  973464     // [1024][100] = 102400
#define SIM5_OFF  1075864    // [5][1024][70] = 358400
#define PW_OFF    1434264    // [1024][70] = 71680
#define PQ4_OFF   1505944    // [4][1024][5][64] = 1310720
#define PQ_OFF    2816664    // [1024][5][64] = 327680
#define CLS_OFF   3144344    // [1024]
#define ALN_OFF   3145368    // [1024]

#define PQ_ELEMS (NQ*NWAY*64)
#define SIM_STRIDE (NQ*NPAIR)

__device__ __forceinline__ float redsum64(float x){
  #pragma unroll
  for (int o = 1; o < 64; o <<= 1) x += __shfl_xor(x, o, 64);
  return x;
}

// ---------------- kV: support normalize + vpt + vptT + M + vninv + psum ----------------
__global__ __launch_bounds__(256) void kV(const float* __restrict__ feat,
                                          float* __restrict__ vpt,
                                          float* __restrict__ vptT,
                                          float* __restrict__ MM,
                                          float* __restrict__ vninv,
                                          float* __restrict__ psum){
  __shared__ float lds[64*101];
  __shared__ float inv[100];
  __shared__ float red[4];
  int pair = blockIdx.x;
  int n = pair / PRJ, v = pair - n*PRJ;
  int t = threadIdx.x;
  float acc[25];
  #pragma unroll
  for (int i = 0; i < 25; i++) acc[i] = 0.f;

  for (int k = 0; k < KSHOT; k++){
    int s = (n*KSHOT + k)*PRJ + v;
    const float* fp = feat + (size_t)s * 6400;
    #pragma unroll
    for (int i = 0; i < 25; i++){
      int j = t + 256*i;
      int d = j / 100, p = j - d*100;
      lds[d*101 + p] = fp[j];
    }
    __syncthreads();
    if (t < 100){
      float ss = 0.f;
      #pragma unroll
      for (int d = 0; d < 64; d++){ float x = lds[d*101 + t]; ss += x*x; }
      inv[t] = 1.f / fmaxf(sqrtf(ss), 1e-12f);
    }
    __syncthreads();
    #pragma unroll
    for (int i = 0; i < 25; i++){
      int j = t + 256*i;
      int p = j >> 6, d = j & 63;
      acc[i] += lds[d*101 + p] * inv[p];
    }
    __syncthreads();
  }
  float ssq = 0.f;
  #pragma unroll
  for (int i = 0; i < 25; i++){
    int j = t + 256*i;
    int p = j >> 6, d = j & 63;
    float val = acc[i] * 0.2f;
    vpt[(size_t)pair*6400 + j] = val;
    lds[d*101 + p] = val;
    ssq += val*val;
  }
  ssq = redsum64(ssq);
  if ((t & 63) == 0) red[t >> 6] = ssq;
  __syncthreads();
  if (t == 0){
    float tot = red[0] + red[1] + red[2] + red[3];
    vninv[pair] = 1.f / fmaxf(sqrtf(tot), 1e-12f);
  }
  #pragma unroll
  for (int i = 0; i < 25; i++){
    int f = t + 256*i;
    int d = f / 100;
    vptT[(size_t)pair*6400 + f] = lds[f + d];
  }
  if (t < 100){
    float s = 0.f;
    #pragma unroll
    for (int d = 0; d < 64; d++) s += lds[d*101 + t];
    MM[pair*100 + t] = s * (1.f/64.f);
  }
  if (t >= 128 && t < 192){
    int d = t - 128;
    float s = 0.f;
    #pragma unroll
    for (int p = 0; p < PP; p++) s += lds[d*101 + p];
    psum[pair*64 + d] = s;
  }
}

// ---------------- kB: tiny reduce of psum -> base ----------------
__global__ __launch_bounds__(320) void kB(const float* __restrict__ psum,
                                          float* __restrict__ base){
  int t = threadIdx.x;
  int n = t >> 6, d = t & 63;
  float s = 0.f;
  #pragma unroll
  for (int v = 0; v < PRJ; v++) s += psum[(n*PRJ + v)*64 + d];
  base[t] = s * (1.f/1400.f);
}

// ---------------- kQ: per-query inv norms + query_vec ----------------
__global__ __launch_bounds__(256) void kQ(const float* __restrict__ feat,
                                          float* __restrict__ invq,
                                          float* __restrict__ qv){
  __shared__ float lds[64*101];
  __shared__ float inv[100];
  int q = blockIdx.x, t = threadIdx.x;
  const float* fp = feat + (size_t)(NS + q) * 6400;
  #pragma unroll
  for (int i = 0; i < 25; i++){
    int j = t + 256*i;
    int d = j / 100, p = j - d*100;
    lds[d*101 + p] = fp[j];
  }
  __syncthreads();
  if (t < 100){
    float ss = 0.f;
    #pragma unroll
    for (int d = 0; d < 64; d++){ float x = lds[d*101 + t]; ss += x*x; }
    float iv = 1.f / fmaxf(sqrtf(ss), 1e-12f);
    inv[t] = iv;
    invq[q*100 + t] = iv;
  }
  __syncthreads();
  if (t < 64){
    float s = 0.f;
    for (int p = 0; p < PP; p++) s += lds[t*101 + p] * inv[p];
    qv[q*64 + t] = s * 0.01f;
  }
}

// ---------------- kS v3: K-split x5 -> sim5 partials ----------------
// grid 1280: b -> c = b>>8 (f-chunk), r = b&255 -> qg = r>>1 (8 q), ph = r&1 (35 pairs)
__global__ __launch_bounds__(256) void kS(const float* __restrict__ feat,
                                          const float* __restrict__ invq,
                                          const float* __restrict__ vptT,
                                          float* __restrict__ sim5){
  __shared__ float A[8*1280];
  __shared__ float inv_l[800];
  int b = blockIdx.x;
  int c  = b >> 8;
  int r  = b & 255;
  int qg = r >> 1, ph = r & 1;
  int q0 = qg * 8;
  int t = threadIdx.x;
  int w = t >> 6, l = t & 63;

  for (int i = t; i < 800; i += 256) inv_l[i] = invq[q0*100 + i];

  int npr = (w < 3) ? 9 : 8;
  int prs = ph*35 + w*9;

  float acc[8][9];
  #pragma unroll
  for (int q = 0; q < 8; q++)
    #pragma unroll
    for (int j = 0; j < 9; j++) acc[q][j] = 0.f;

  const float4* fq4 = (const float4*)(feat + (size_t)NS*6400);
  const float4* B4  = (const float4*)vptT;
  float4* A4 = (float4*)A;

  int f0 = c * 1280;
  __syncthreads();
  #pragma unroll
  for (int i = 0; i < 10; i++){
    int fi = i*256 + t;
    int q  = fi / 320, c4 = fi - q*320;
    float4 vv = fq4[(size_t)(q0+q)*1600 + (f0>>2) + c4];
    int fb = f0 + c4*4;
    float r0 = vv.x, r1 = vv.y, r2 = vv.z, r3 = vv.w;
    int p0 = fb % 100;
    int p1 = (fb+1) % 100;
    int p2 = (fb+2) % 100;
    int p3 = (fb+3) % 100;
    r0 *= inv_l[q*100 + p0];
    r1 *= inv_l[q*100 + p1];
    r2 *= inv_l[q*100 + p2];
    r3 *= inv_l[q*100 + p3];
    A4[q*320 + c4] = make_float4(r0, r1, r2, r3);
  }
  __syncthreads();
  for (int s = 0; s < 5; s++){
    float4 a4[8];
    #pragma unroll
    for (int q = 0; q < 8; q++) a4[q] = A4[q*320 + s*64 + l];
    #pragma unroll
    for (int j = 0; j < 9; j++){
      if (j < npr){
        float4 b4 = B4[(size_t)(prs+j)*1600 + (f0>>2) + s*64 + l];
        #pragma unroll
        for (int q = 0; q < 8; q++)
          acc[q][j] += a4[q].x*b4.x + a4[q].y*b4.y + a4[q].z*b4.z + a4[q].w*b4.w;
      }
    }
  }
  #pragma unroll
  for (int q = 0; q < 8; q++)
    #pragma unroll
    for (int j = 0; j < 9; j++){
      if (j < npr){
        float s = redsum64(acc[q][j]);
        if (l == 0) sim5[(size_t)c*SIM_STRIDE + (q0+q)*NPAIR + prs + j] = s;
      }
    }
}

// ---------------- kM: sum K-split partials + per-(q,n) softmax over 14 views ----------------
__global__ __launch_bounds__(256) void kM(const float* __restrict__ sim5,
                                          const float* __restrict__ vninv,
                                          const float* __restrict__ temp,
                                          float* __restrict__ pw){
  int t = blockIdx.x*256 + threadIdx.x;
  if (t >= NQ*NWAY) return;
  int q = t / NWAY, n = t - q*NWAY;
  float invT = 1.f / (temp[0] + 1e-6f);
  float s[PRJ];
  float m = -3.4e38f;
  #pragma unroll
  for (int v = 0; v < PRJ; v++){
    int pr = n*PRJ + v;
    float sv = 0.f;
    #pragma unroll
    for (int c = 0; c < KSPLIT; c++)
      sv += sim5[(size_t)c*SIM_STRIDE + q*NPAIR + pr];
    s[v] = sv * vninv[pr] * invT;
    m = fmaxf(m, s[v]);
  }
  float sum = 0.f;
  #pragma unroll
  for (int v = 0; v < PRJ; v++){ s[v] = expf(s[v] - m); sum += s[v]; }
  float rs = 1.f / sum;
  #pragma unroll
  for (int v = 0; v < PRJ; v++) pw[q*NPAIR + n*PRJ + v] = s[v] * rs;
}

// ---------------- kP: p-split 4x, sg computed inline, partial outputs ----------------
__global__ __launch_bounds__(256) void kP(const float* __restrict__ vpt,
                                          const float* __restrict__ pw,
                                          const float* __restrict__ MM,
                                          float* __restrict__ pq4){
  __shared__ float sgl[16][PCHUNK];
  int b = blockIdx.x;
  int n  = b / 256;
  int r  = b - n*256;
  int qb = r >> 2;
  int s  = r & 3;
  int p0 = s * PCHUNK;
  int t = threadIdx.x, w = t >> 6, l = t & 63;
  int q0 = qb*16 + w*4;

  float wq[4][PRJ];
  #pragma unroll
  for (int j = 0; j < 4; j++)
    #pragma unroll
    for (int v = 0; v < PRJ; v++)
      wq[j][v] = pw[(q0+j)*NPAIR + n*PRJ + v];

  if (l < PCHUNK){
    #pragma unroll
    for (int j = 0; j < 4; j++){
      float ssg = 0.f;
      #pragma unroll
      for (int v = 0; v < PRJ; v++)
        ssg += wq[j][v] * MM[(n*PRJ + v)*100 + p0 + l];
      sgl[w*4 + j][l] = 1.f / (1.f + expf(-ssg));
    }
  }
  __syncthreads();

  float acc[4] = {0.f, 0.f, 0.f, 0.f};
  const float* vb = vpt + (size_t)n * PRJ * 6400;
  for (int pl = 0; pl < PCHUNK; pl++){
    int p = p0 + pl;
    float vv[PRJ];
    #pragma unroll
    for (int v = 0; v < PRJ; v++) vv[v] = vb[v*6400 + p*64 + l];
    #pragma unroll
    for (int j = 0; j < 4; j++){
      float dot = 0.f;
      #pragma unroll
      for (int v = 0; v < PRJ; v++) dot += wq[j][v] * vv[v];
      acc[j] += sgl[w*4 + j][pl] * dot;
    }
  }
  #pragma unroll
  for (int j = 0; j < 4; j++)
    pq4[(size_t)s*PQ_ELEMS + ((q0+j)*NWAY + n)*64 + l] = acc[j];
}

// ---------------- kPr: reduce 4 p-split partials ----------------
__global__ __launch_bounds__(256) void kPr(const float* __restrict__ pq4,
                                           float* __restrict__ pq){
  int idx = blockIdx.x*256 + threadIdx.x;
  float s = pq4[idx] + pq4[PQ_ELEMS + idx] + pq4[2*PQ_ELEMS + idx] + pq4[3*PQ_ELEMS + idx];
  pq[idx] = s;
}

// ---------------- kF: per-query epilogue ----------------
__global__ __launch_bounds__(64) void kF(const float* __restrict__ qv,
                                         const float* __restrict__ pqw,
                                         const float* __restrict__ base,
                                         const float* __restrict__ Wq,
                                         const float* __restrict__ bq,
                                         const float* __restrict__ Wk,
                                         const float* __restrict__ bk,
                                         const float* __restrict__ gate,
                                         const int*   __restrict__ label,
                                         float* __restrict__ pred,
                                         float* __restrict__ cls,
                                         float* __restrict__ aln){
  __shared__ float qvl[64];
  __shared__ float qp[16];
  __shared__ float dl[64];
  int q = blockIdx.x, l = threadIdx.x;

  float qvv = qv[q*64 + l];
  qvl[l] = qvv;
  __syncthreads();
  float qss = redsum64(qvv*qvv);
  float qn8 = fmaxf(sqrtf(qss), 1e-8f);

  if (l < 16){
    float s = bq[l];
    #pragma unroll
    for (int d = 0; d < 64; d++) s += qvl[d] * Wq[d*16 + l];
    qp[l] = s;
  }
  __syncthreads();

  float wkq = 0.f;
  #pragma unroll
  for (int e = 0; e < 16; e++) wkq += Wk[l*16 + e] * qp[e];
  float qpb = 0.f;
  #pragma unroll
  for (int e = 0; e < 16; e++) qpb += qp[e] * bk[e];

  float pqv[NWAY], cosv[NWAY], sc[NWAY];
  #pragma unroll
  for (int n = 0; n < NWAY; n++){
    float x = pqw[(q*NWAY + n)*64 + l];
    pqv[n] = x;
    float dq = redsum64(qvv * x);
    float ps = redsum64(x * x);
    cosv[n] = dq / (qn8 * fmaxf(sqrtf(ps), 1e-8f));
    float sd = redsum64(x * wkq);
    sc[n] = (sd + qpb) * 0.25f;
  }

  float am = sc[0];
  #pragma unroll
  for (int n = 1; n < NWAY; n++) am = fmaxf(am, sc[n]);
  float ae[NWAY], asum = 0.f;
  #pragma unroll
  for (int n = 0; n < NWAY; n++){ ae[n] = expf(sc[n] - am); asum += ae[n]; }
  float rasum = 1.f / asum;

  float g0 = gate[0], g1 = gate[1], g2 = gate[2];
  float gm = fmaxf(fmaxf(g0, g1), g2);
  float e0 = expf(g0 - gm), e1 = expf(g1 - gm), e2 = expf(g2 - gm);
  float gs = 1.f / (e0 + e1 + e2);
  float b0 = (e0 + e1 + e2) * gs;
  float b1 = (e1 + e2) * gs;
  float b2 = e2 * gs;

  float cos2[NWAY];
  #pragma unroll
  for (int n = 0; n < NWAY; n++){
    float f  = pqv[n] * (ae[n] * rasum);
    float dd = fabsf(f - base[n*64 + l]);
    dl[l] = dd;
    __syncthreads();
    int rank = 0;
    #pragma unroll 8
    for (int j = 0; j < 64; j++){
      float dj = dl[j];
      rank += (dj > dd) || (dj == dd && j < l);
    }
    __syncthreads();
    float cw = (rank < 16) ? b0 : (rank < 32) ? b1 : (rank < 48) ? b2 : 0.f;
    float gl = f * cw;
    float gss = redsum64(gl * gl);
    float num = redsum64(qvv * gl);
    cos2[n] = num / (qn8 * fmaxf(sqrtf(gss), 1e-12f));
  }

  float mx = cos2[0];
  #pragma unroll
  for (int n = 1; n < NWAY; n++) mx = fmaxf(mx, cos2[n]);
  float pe[NWAY], psum = 0.f;
  #pragma unroll
  for (int n = 0; n < NWAY; n++){ pe[n] = expf(cos2[n] - mx); psum += pe[n]; }
  float rp = 1.f / psum;
  if (l == 0){
    #pragma unroll
    for (int n = 0; n < NWAY; n++) pred[q*NWAY + n] = pe[n] * rp;
  }

  int lab = label[q];
  float lm = LAMDA * mx;
  float lsum = 0.f;
  #pragma unroll
  for (int n = 0; n < NWAY; n++) lsum += expf(LAMDA * cos2[n] - lm);
  float c2l = cos2[0], cosl = cosv[0];
  #pragma unroll
  for (int n = 1; n < NWAY; n++){
    if (lab == n){ c2l = cos2[n]; cosl = cosv[n]; }
  }
  float clsv = (lm + logf(lsum)) - LAMDA * c2l;

  float sum5 = 0.f, minn = 3.4e38f;
  #pragma unroll
  for (int n = 0; n < NWAY; n++){
    sum5 += cosv[n];
    if (n != lab) minn = fminf(minn, cosv[n]);
  }
  float hn = (sum5 - cosl - minn) * (1.f/3.f);
  float al = fmaxf(hn - cosl + MARGIN, 0.f);
  if (l == 0){ cls[q] = clsv; aln[q] = al; }
}

// ---------------- kL: loss reduction ----------------
__global__ __launch_bounds__(256) void kL(const float* __restrict__ cls,
                                          const float* __restrict__ aln,
                                          float* __restrict__ out){
  __shared__ float r1[256], r2[256];
  int t = threadIdx.x;
  float s1 = 0.f, s2 = 0.f;
  for (int i = t; i < NQ; i += 256){ s1 += cls[i]; s2 += aln[i]; }
  r1[t] = s1; r2[t] = s2;
  __syncthreads();
  for (int o = 128; o > 0; o >>= 1){
    if (t < o){ r1[t] += r1[t + o]; r2[t] += r2[t + o]; }
    __syncthreads();
  }
  if (t == 0)
    out[NQ*NWAY] = r1[0]*(1.f/NQ) + 0.3f*(r2[0]*(1.f/NQ));
}

extern "C" void kernel_launch(void* const* d_in, const int* in_sizes, int n_in,
                              void* d_out, int out_size, void* d_ws, size_t ws_size,
                              hipStream_t stream){
  const float* feat = (const float*)d_in[0];
  const float* temp = (const float*)d_in[1];
  const float* gate = (const float*)d_in[2];
  const float* Wq   = (const float*)d_in[3];
  const float* bq   = (const float*)d_in[4];
  const float* Wk   = (const float*)d_in[5];
  const float* bk   = (const float*)d_in[6];
  const int*   lab  = (const int*)d_in[7];
  float* out = (float*)d_out;
  float* ws  = (float*)d_ws;

  float* vpt   = ws + VPT_OFF;
  float* vptT  = ws + VPTT_OFF;
  float* MMp   = ws + MM_OFF;
  float* vninv = ws + VNINV_OFF;
  float* psum  = ws + PSUM_OFF;
  float* base  = ws + BASE_OFF;
  float* qv    = ws + QV_OFF;
  float* invq  = ws + INVQ_OFF;
  float* sim5  = ws + SIM5_OFF;
  float* pw    = ws + PW_OFF;
  float* pq4   = ws + PQ4_OFF;
  float* pq    = ws + PQ_OFF;
  float* cls   = ws + CLS_OFF;
  float* aln   = ws + ALN_OFF;

  hipLaunchKernelGGL(kV, dim3(NPAIR), dim3(256), 0, stream, feat, vpt, vptT, MMp, vninv, psum);
  hipLaunchKernelGGL(kB, dim3(1), dim3(320), 0, stream, psum, base);
  hipLaunchKernelGGL(kQ, dim3(NQ), dim3(256), 0, stream, feat, invq, qv);
  hipLaunchKernelGGL(kS, dim3(KSPLIT*256), dim3(256), 0, stream, feat, invq, vptT, sim5);
  hipLaunchKernelGGL(kM, dim3((NQ*NWAY + 255)/256), dim3(256), 0, stream, sim5, vninv, temp, pw);
  hipLaunchKernelGGL(kP, dim3(NWAY*256), dim3(256), 0, stream, vpt, pw, MMp, pq4);
  hipLaunchKernelGGL(kPr, dim3(PQ_ELEMS/256), dim3(256), 0, stream, pq4, pq);
  hipLaunchKernelGGL(kF, dim3(NQ), dim3(64), 0, stream, qv, pq, base, Wq, bq, Wk, bk, gate, lab, out, cls, aln);
  hipLaunchKernelGGL(kL, dim3(1), dim3(256), 0, stream, cls, aln, out);
}

// Round 6
// 131.436 us; speedup vs baseline: 1.5666x; 1.5666x over previous
//
#include <hip/hip_runtime.h>
#include <math.h>

#define NWAY 5
#define KSHOT 5
#define PRJ 14
#define DD 64
#define PP 100
#define NQ 1024
#define NS 350
#define NPAIR 70
#define LAMDA 32.0f
#define MARGIN 0.3f
#define PCHUNK 25
#define FGROUPS 32
#define SUBCH 2

// ---- workspace layout (floats), ~22.5 MB ----
#define VPT_OFF   0          // [70][100][64]  = 448000
#define VPTT_OFF  448000     // [70][6400]     = 448000
#define B2_OFF    896000     // [6400][72]     = 460800 (pair-contig, padded)
#define MM_OFF    1356800    // [70][100]      = 7000
#define VNINV_OFF 1363800    // [70] pad 128
#define PSUM_OFF  1363928    // [70][64] = 4480
#define BASE_OFF  1368408    // [5][64]
#define QV_OFF    1368728    // [1024][64] = 65536
#define INVQ_OFF  1434264    // [1024][100] = 102400
#define SIM32_OFF 1536664    // [32][1024][70] = 2293760
#define SIM_OFF   3830424    // [1024][70] = 71680
#define PW_OFF    3902104    // [1024][70] = 71680
#define PQ4_OFF   3973784    // [4][1024][5][64] = 1310720
#define PQ_OFF    5284504    // [1024][5][64] = 327680
#define CLS_OFF   5612184    // [1024]
#define ALN_OFF   5613208    // [1024]

#define PQ_ELEMS (NQ*NWAY*64)
#define SIM_STRIDE (NQ*NPAIR)

__device__ __forceinline__ float redsum64(float x){
  #pragma unroll
  for (int o = 1; o < 64; o <<= 1) x += __shfl_xor(x, o, 64);
  return x;
}

// ---------------- kV: support normalize + vpt + vptT + M + vninv + psum ----------------
__global__ __launch_bounds__(256) void kV(const float* __restrict__ feat,
                                          float* __restrict__ vpt,
                                          float* __restrict__ vptT,
                                          float* __restrict__ MM,
                                          float* __restrict__ vninv,
                                          float* __restrict__ psum){
  __shared__ float lds[64*101];
  __shared__ float inv[100];
  __shared__ float red[4];
  int pair = blockIdx.x;
  int n = pair / PRJ, v = pair - n*PRJ;
  int t = threadIdx.x;
  float acc[25];
  #pragma unroll
  for (int i = 0; i < 25; i++) acc[i] = 0.f;

  for (int k = 0; k < KSHOT; k++){
    int s = (n*KSHOT + k)*PRJ + v;
    const float* fp = feat + (size_t)s * 6400;
    #pragma unroll
    for (int i = 0; i < 25; i++){
      int j = t + 256*i;
      int d = j / 100, p = j - d*100;
      lds[d*101 + p] = fp[j];
    }
    __syncthreads();
    if (t < 100){
      float ss = 0.f;
      #pragma unroll
      for (int d = 0; d < 64; d++){ float x = lds[d*101 + t]; ss += x*x; }
      inv[t] = 1.f / fmaxf(sqrtf(ss), 1e-12f);
    }
    __syncthreads();
    #pragma unroll
    for (int i = 0; i < 25; i++){
      int j = t + 256*i;
      int p = j >> 6, d = j & 63;
      acc[i] += lds[d*101 + p] * inv[p];
    }
    __syncthreads();
  }
  float ssq = 0.f;
  #pragma unroll
  for (int i = 0; i < 25; i++){
    int j = t + 256*i;
    int p = j >> 6, d = j & 63;
    float val = acc[i] * 0.2f;
    vpt[(size_t)pair*6400 + j] = val;
    lds[d*101 + p] = val;
    ssq += val*val;
  }
  ssq = redsum64(ssq);
  if ((t & 63) == 0) red[t >> 6] = ssq;
  __syncthreads();
  if (t == 0){
    float tot = red[0] + red[1] + red[2] + red[3];
    vninv[pair] = 1.f / fmaxf(sqrtf(tot), 1e-12f);
  }
  #pragma unroll
  for (int i = 0; i < 25; i++){
    int f = t + 256*i;
    int d = f / 100;
    vptT[(size_t)pair*6400 + f] = lds[f + d];
  }
  if (t < 100){
    float s = 0.f;
    #pragma unroll
    for (int d = 0; d < 64; d++) s += lds[d*101 + t];
    MM[pair*100 + t] = s * (1.f/64.f);
  }
  if (t >= 128 && t < 192){
    int d = t - 128;
    float s = 0.f;
    #pragma unroll
    for (int p = 0; p < PP; p++) s += lds[d*101 + p];
    psum[pair*64 + d] = s;
  }
}

// ---------------- kB: tiny reduce of psum -> base ----------------
__global__ __launch_bounds__(320) void kB(const float* __restrict__ psum,
                                          float* __restrict__ base){
  int t = threadIdx.x;
  int n = t >> 6, d = t & 63;
  float s = 0.f;
  #pragma unroll
  for (int v = 0; v < PRJ; v++) s += psum[(n*PRJ + v)*64 + d];
  base[t] = s * (1.f/1400.f);
}

// ---------------- kQ: per-query inv norms + query_vec ----------------
__global__ __launch_bounds__(256) void kQ(const float* __restrict__ feat,
                                          float* __restrict__ invq,
                                          float* __restrict__ qv){
  __shared__ float lds[64*101];
  __shared__ float inv[100];
  int q = blockIdx.x, t = threadIdx.x;
  const float* fp = feat + (size_t)(NS + q) * 6400;
  #pragma unroll
  for (int i = 0; i < 25; i++){
    int j = t + 256*i;
    int d = j / 100, p = j - d*100;
    lds[d*101 + p] = fp[j];
  }
  __syncthreads();
  if (t < 100){
    float ss = 0.f;
    #pragma unroll
    for (int d = 0; d < 64; d++){ float x = lds[d*101 + t]; ss += x*x; }
    float iv = 1.f / fmaxf(sqrtf(ss), 1e-12f);
    inv[t] = iv;
    invq[q*100 + t] = iv;
  }
  __syncthreads();
  if (t < 64){
    float s = 0.f;
    for (int p = 0; p < PP; p++) s += lds[t*101 + p] * inv[p];
    qv[q*64 + t] = s * 0.01f;
  }
}

// ---------------- kT: vptT[pair][f] -> B2[f][72] (pair-contiguous, zero-padded) ----------------
__global__ __launch_bounds__(256) void kT(const float* __restrict__ vptT,
                                          float* __restrict__ B2){
  __shared__ float l2[64*71];
  int b = blockIdx.x;           // 100 chunks of 64 f
  int t = threadIdx.x;
  for (int i = t; i < NPAIR*64; i += 256){
    int pair = i >> 6, fl = i & 63;
    l2[fl*71 + pair] = vptT[(size_t)pair*6400 + b*64 + fl];
  }
  __syncthreads();
  for (int i = t; i < 64*72; i += 256){
    int fl = i / 72, pr = i - fl*72;
    B2[(size_t)(b*64 + fl)*72 + pr] = (pr < NPAIR) ? l2[fl*71 + pr] : 0.f;
  }
}

// ---------------- kS v4: lane=query, scalar-B FMA, f-split 32 ----------------
// grid 512: b -> qg = b&15 (64 queries), fg = b>>4 (200 f). 4 waves x 18 pairs.
__global__ __launch_bounds__(256) void kS(const float* __restrict__ feat,
                                          const float* __restrict__ invq,
                                          const float* __restrict__ B2,
                                          float* __restrict__ sim32){
  __shared__ float A[100*66];
  int b = blockIdx.x;
  int qg = b & 15, fg = b >> 4;
  int q0 = qg * 64;
  int t = threadIdx.x;
  int l = t & 63;
  int wu = __builtin_amdgcn_readfirstlane(t >> 6);
  int pr0 = wu * 18;

  float acc[18];
  #pragma unroll
  for (int j = 0; j < 18; j++) acc[j] = 0.f;

  for (int cc = 0; cc < SUBCH; cc++){
    int fbase = (fg*SUBCH + cc) * 100;
    __syncthreads();
    for (int i = t; i < 1600; i += 256){
      int q = i / 25, r4 = i - q*25;
      float4 f4 = *(const float4*)(feat + (size_t)(NS + q0 + q)*6400 + fbase + r4*4);
      float4 v4 = *(const float4*)(invq + (q0 + q)*100 + r4*4);
      A[(r4*4+0)*66 + q] = f4.x * v4.x;
      A[(r4*4+1)*66 + q] = f4.y * v4.y;
      A[(r4*4+2)*66 + q] = f4.z * v4.z;
      A[(r4*4+3)*66 + q] = f4.w * v4.w;
    }
    __syncthreads();
    const float* Bb = B2 + (size_t)fbase*72 + pr0;   // wave-uniform -> s_load
    for (int r = 0; r < 100; r++){
      float a = A[r*66 + l];
      #pragma unroll
      for (int j = 0; j < 18; j++)
        acc[j] += a * Bb[r*72 + j];
    }
  }
  int qq = q0 + l;
  #pragma unroll
  for (int j = 0; j < 18; j++){
    int pr = pr0 + j;
    if (pr < NPAIR) sim32[(size_t)fg*SIM_STRIDE + qq*NPAIR + pr] = acc[j];
  }
}

// ---------------- kSr: reduce 32 f-group partials -> sim ----------------
__global__ __launch_bounds__(256) void kSr(const float* __restrict__ sim32,
                                           float* __restrict__ sim){
  int idx = blockIdx.x*256 + threadIdx.x;   // 71680
  float s = 0.f;
  #pragma unroll
  for (int c = 0; c < FGROUPS; c++) s += sim32[(size_t)c*SIM_STRIDE + idx];
  sim[idx] = s;
}

// ---------------- kM: per-(q,n) softmax over 14 views ----------------
__global__ __launch_bounds__(256) void kM(const float* __restrict__ sim,
                                          const float* __restrict__ vninv,
                                          const float* __restrict__ temp,
                                          float* __restrict__ pw){
  int t = blockIdx.x*256 + threadIdx.x;
  if (t >= NQ*NWAY) return;
  int q = t / NWAY, n = t - q*NWAY;
  float invT = 1.f / (temp[0] + 1e-6f);
  float s[PRJ];
  float m = -3.4e38f;
  #pragma unroll
  for (int v = 0; v < PRJ; v++){
    int pr = n*PRJ + v;
    s[v] = sim[q*NPAIR + pr] * vninv[pr] * invT;
    m = fmaxf(m, s[v]);
  }
  float sum = 0.f;
  #pragma unroll
  for (int v = 0; v < PRJ; v++){ s[v] = expf(s[v] - m); sum += s[v]; }
  float rs = 1.f / sum;
  #pragma unroll
  for (int v = 0; v < PRJ; v++) pw[q*NPAIR + n*PRJ + v] = s[v] * rs;
}

// ---------------- kP: p-split 4x, sg computed inline, partial outputs ----------------
__global__ __launch_bounds__(256) void kP(const float* __restrict__ vpt,
                                          const float* __restrict__ pw,
                                          const float* __restrict__ MM,
                                          float* __restrict__ pq4){
  __shared__ float sgl[16][PCHUNK];
  int b = blockIdx.x;
  int n  = b / 256;
  int r  = b - n*256;
  int qb = r >> 2;
  int s  = r & 3;
  int p0 = s * PCHUNK;
  int t = threadIdx.x, w = t >> 6, l = t & 63;
  int q0 = qb*16 + w*4;

  float wq[4][PRJ];
  #pragma unroll
  for (int j = 0; j < 4; j++)
    #pragma unroll
    for (int v = 0; v < PRJ; v++)
      wq[j][v] = pw[(q0+j)*NPAIR + n*PRJ + v];

  if (l < PCHUNK){
    #pragma unroll
    for (int j = 0; j < 4; j++){
      float ssg = 0.f;
      #pragma unroll
      for (int v = 0; v < PRJ; v++)
        ssg += wq[j][v] * MM[(n*PRJ + v)*100 + p0 + l];
      sgl[w*4 + j][l] = 1.f / (1.f + expf(-ssg));
    }
  }
  __syncthreads();

  float acc[4] = {0.f, 0.f, 0.f, 0.f};
  const float* vb = vpt + (size_t)n * PRJ * 6400;
  for (int pl = 0; pl < PCHUNK; pl++){
    int p = p0 + pl;
    float vv[PRJ];
    #pragma unroll
    for (int v = 0; v < PRJ; v++) vv[v] = vb[v*6400 + p*64 + l];
    #pragma unroll
    for (int j = 0; j < 4; j++){
      float dot = 0.f;
      #pragma unroll
      for (int v = 0; v < PRJ; v++) dot += wq[j][v] * vv[v];
      acc[j] += sgl[w*4 + j][pl] * dot;
    }
  }
  #pragma unroll
  for (int j = 0; j < 4; j++)
    pq4[(size_t)s*PQ_ELEMS + ((q0+j)*NWAY + n)*64 + l] = acc[j];
}

// ---------------- kPr: reduce 4 p-split partials ----------------
__global__ __launch_bounds__(256) void kPr(const float* __restrict__ pq4,
                                           float* __restrict__ pq){
  int idx = blockIdx.x*256 + threadIdx.x;
  float s = pq4[idx] + pq4[PQ_ELEMS + idx] + pq4[2*PQ_ELEMS + idx] + pq4[3*PQ_ELEMS + idx];
  pq[idx] = s;
}

// ---------------- kF: per-query epilogue ----------------
__global__ __launch_bounds__(64) void kF(const float* __restrict__ qv,
                                         const float* __restrict__ pqw,
                                         const float* __restrict__ base,
                                         const float* __restrict__ Wq,
                                         const float* __restrict__ bq,
                                         const float* __restrict__ Wk,
                                         const float* __restrict__ bk,
                                         const float* __restrict__ gate,
                                         const int*   __restrict__ label,
                                         float* __restrict__ pred,
                                         float* __restrict__ cls,
                                         float* __restrict__ aln){
  __shared__ float qvl[64];
  __shared__ float qp[16];
  __shared__ float dl[64];
  int q = blockIdx.x, l = threadIdx.x;

  float qvv = qv[q*64 + l];
  qvl[l] = qvv;
  __syncthreads();
  float qss = redsum64(qvv*qvv);
  float qn8 = fmaxf(sqrtf(qss), 1e-8f);

  if (l < 16){
    float s = bq[l];
    #pragma unroll
    for (int d = 0; d < 64; d++) s += qvl[d] * Wq[d*16 + l];
    qp[l] = s;
  }
  __syncthreads();

  float wkq = 0.f;
  #pragma unroll
  for (int e = 0; e < 16; e++) wkq += Wk[l*16 + e] * qp[e];
  float qpb = 0.f;
  #pragma unroll
  for (int e = 0; e < 16; e++) qpb += qp[e] * bk[e];

  float pqv[NWAY], cosv[NWAY], sc[NWAY];
  #pragma unroll
  for (int n = 0; n < NWAY; n++){
    float x = pqw[(q*NWAY + n)*64 + l];
    pqv[n] = x;
    float dq = redsum64(qvv * x);
    float ps = redsum64(x * x);
    cosv[n] = dq / (qn8 * fmaxf(sqrtf(ps), 1e-8f));
    float sd = redsum64(x * wkq);
    sc[n] = (sd + qpb) * 0.25f;
  }

  float am = sc[0];
  #pragma unroll
  for (int n = 1; n < NWAY; n++) am = fmaxf(am, sc[n]);
  float ae[NWAY], asum = 0.f;
  #pragma unroll
  for (int n = 0; n < NWAY; n++){ ae[n] = expf(sc[n] - am); asum += ae[n]; }
  float rasum = 1.f / asum;

  float g0 = gate[0], g1 = gate[1], g2 = gate[2];
  float gm = fmaxf(fmaxf(g0, g1), g2);
  float e0 = expf(g0 - gm), e1 = expf(g1 - gm), e2 = expf(g2 - gm);
  float gs = 1.f / (e0 + e1 + e2);
  float b0 = (e0 + e1 + e2) * gs;
  float b1 = (e1 + e2) * gs;
  float b2 = e2 * gs;

  float cos2[NWAY];
  #pragma unroll
  for (int n = 0; n < NWAY; n++){
    float f  = pqv[n] * (ae[n] * rasum);
    float dd = fabsf(f - base[n*64 + l]);
    dl[l] = dd;
    __syncthreads();
    int rank = 0;
    #pragma unroll 8
    for (int j = 0; j < 64; j++){
      float dj = dl[j];
      rank += (dj > dd) || (dj == dd && j < l);
    }
    __syncthreads();
    float cw = (rank < 16) ? b0 : (rank < 32) ? b1 : (rank < 48) ? b2 : 0.f;
    float gl = f * cw;
    float gss = redsum64(gl * gl);
    float num = redsum64(qvv * gl);
    cos2[n] = num / (qn8 * fmaxf(sqrtf(gss), 1e-12f));
  }

  float mx = cos2[0];
  #pragma unroll
  for (int n = 1; n < NWAY; n++) mx = fmaxf(mx, cos2[n]);
  float pe[NWAY], psum = 0.f;
  #pragma unroll
  for (int n = 0; n < NWAY; n++){ pe[n] = expf(cos2[n] - mx); psum += pe[n]; }
  float rp = 1.f / psum;
  if (l == 0){
    #pragma unroll
    for (int n = 0; n < NWAY; n++) pred[q*NWAY + n] = pe[n] * rp;
  }

  int lab = label[q];
  float lm = LAMDA * mx;
  float lsum = 0.f;
  #pragma unroll
  for (int n = 0; n < NWAY; n++) lsum += expf(LAMDA * cos2[n] - lm);
  float c2l = cos2[0], cosl = cosv[0];
  #pragma unroll
  for (int n = 1; n < NWAY; n++){
    if (lab == n){ c2l = cos2[n]; cosl = cosv[n]; }
  }
  float clsv = (lm + logf(lsum)) - LAMDA * c2l;

  float sum5 = 0.f, minn = 3.4e38f;
  #pragma unroll
  for (int n = 0; n < NWAY; n++){
    sum5 += cosv[n];
    if (n != lab) minn = fminf(minn, cosv[n]);
  }
  float hn = (sum5 - cosl - minn) * (1.f/3.f);
  float al = fmaxf(hn - cosl + MARGIN, 0.f);
  if (l == 0){ cls[q] = clsv; aln[q] = al; }
}

// ---------------- kL: loss reduction ----------------
__global__ __launch_bounds__(256) void kL(const float* __restrict__ cls,
                                          const float* __restrict__ aln,
                                          float* __restrict__ out){
  __shared__ float r1[256], r2[256];
  int t = threadIdx.x;
  float s1 = 0.f, s2 = 0.f;
  for (int i = t; i < NQ; i += 256){ s1 += cls[i]; s2 += aln[i]; }
  r1[t] = s1; r2[t] = s2;
  __syncthreads();
  for (int o = 128; o > 0; o >>= 1){
    if (t < o){ r1[t] += r1[t + o]; r2[t] += r2[t + o]; }
    __syncthreads();
  }
  if (t == 0)
    out[NQ*NWAY] = r1[0]*(1.f/NQ) + 0.3f*(r2[0]*(1.f/NQ));
}

extern "C" void kernel_launch(void* const* d_in, const int* in_sizes, int n_in,
                              void* d_out, int out_size, void* d_ws, size_t ws_size,
                              hipStream_t stream){
  const float* feat = (const float*)d_in[0];
  const float* temp = (const float*)d_in[1];
  const float* gate = (const float*)d_in[2];
  const float* Wq   = (const float*)d_in[3];
  const float* bq   = (const float*)d_in[4];
  const float* Wk   = (const float*)d_in[5];
  const float* bk   = (const float*)d_in[6];
  const int*   lab  = (const int*)d_in[7];
  float* out = (float*)d_out;
  float* ws  = (float*)d_ws;

  float* vpt   = ws + VPT_OFF;
  float* vptT  = ws + VPTT_OFF;
  float* B2    = ws + B2_OFF;
  float* MMp   = ws + MM_OFF;
  float* vninv = ws + VNINV_OFF;
  float* psum  = ws + PSUM_OFF;
  float* base  = ws + BASE_OFF;
  float* qv    = ws + QV_OFF;
  float* invq  = ws + INVQ_OFF;
  float* sim32 = ws + SIM32_OFF;
  float* sim   = ws + SIM_OFF;
  float* pw    = ws + PW_OFF;
  float* pq4   = ws + PQ4_OFF;
  float* pq    = ws + PQ_OFF;
  float* cls   = ws + CLS_OFF;
  float* aln   = ws + ALN_OFF;

  hipLaunchKernelGGL(kV, dim3(NPAIR), dim3(256), 0, stream, feat, vpt, vptT, MMp, vninv, psum);
  hipLaunchKernelGGL(kB, dim3(1), dim3(320), 0, stream, psum, base);
  hipLaunchKernelGGL(kQ, dim3(NQ), dim3(256), 0, stream, feat, invq, qv);
  hipLaunchKernelGGL(kT, dim3(100), dim3(256), 0, stream, vptT, B2);
  hipLaunchKernelGGL(kS, dim3(16*FGROUPS), dim3(256), 0, stream, feat, invq, B2, sim32);
  hipLaunchKernelGGL(kSr, dim3(NQ*NPAIR/256), dim3(256), 0, stream, sim32, sim);
  hipLaunchKernelGGL(kM, dim3((NQ*NWAY + 255)/256), dim3(256), 0, stream, sim, vninv, temp, pw);
  hipLaunchKernelGGL(kP, dim3(NWAY*256), dim3(256), 0, stream, vpt, pw, MMp, pq4);
  hipLaunchKernelGGL(kPr, dim3(PQ_ELEMS/256), dim3(256), 0, stream, pq4, pq);
  hipLaunchKernelGGL(kF, dim3(NQ), dim3(64), 0, stream, qv, pq, base, Wq, bq, Wk, bk, gate, lab, out, cls, aln);
  hipLaunchKernelGGL(kL, dim3(1), dim3(256), 0, stream, cls, aln, out);
}